// Round 1
// baseline (144.582 us; speedup 1.0000x reference)
//
#include <hip/hip_runtime.h>

#define D 512
#define NH 8
#define DH 64
#define CCTX 64
#define LN_EPS 1e-5f

// workspace layout (float offsets)
#define WS_QH    0        // 512
#define WS_T     512      // 8
#define WS_M     1024     // 4096
#define WS_CTX   5120     // 64*512 = 32768
#define WS_CBAR  37888    // 4096
#define WS_O     41984    // 512
#define WS_OUT1  42496    // 512
#define WS_V     43008    // 512
#define WS_ATTN2 43520    // 512

__device__ __forceinline__ float waveReduceSum(float v) {
#pragma unroll
    for (int off = 32; off > 0; off >>= 1) v += __shfl_xor(v, off);
    return v;
}

// Kernel A: blocks 0..127 compute qh = Wq@path + bq (wave per row);
//           blocks 128..191 gather ctx rows H[ids[j]] -> ws (coalesced, L2-warm for later)
__global__ __launch_bounds__(256) void k_qh_gather(
    const float* __restrict__ Win1, const float* __restrict__ bin1,
    const float* __restrict__ path, const float* __restrict__ Hm,
    const int* __restrict__ ids, float* __restrict__ ws)
{
    if (blockIdx.x < 128) {
        int wid  = blockIdx.x * 4 + (threadIdx.x >> 6);   // row 0..511
        int lane = threadIdx.x & 63;
        const float* Wr = Win1 + (size_t)wid * D;
        float4 w0 = *(const float4*)(Wr + lane * 4);
        float4 w1 = *(const float4*)(Wr + 256 + lane * 4);
        float4 x0 = *(const float4*)(path + lane * 4);
        float4 x1 = *(const float4*)(path + 256 + lane * 4);
        float s = w0.x*x0.x + w0.y*x0.y + w0.z*x0.z + w0.w*x0.w
                + w1.x*x1.x + w1.y*x1.y + w1.z*x1.z + w1.w*x1.w;
        s = waveReduceSum(s);
        if (lane == 0) ws[WS_QH + wid] = s + bin1[wid];
    } else {
        int j = blockIdx.x - 128;                          // 0..63
        if (threadIdx.x < 128) {
            int id = ids[j];
            float4 v = *(const float4*)(Hm + (size_t)id * D + threadIdx.x * 4);
            *(float4*)(ws + WS_CTX + j * D + threadIdx.x * 4) = v;
        }
    }
}

// Kernel B: m[h][c] = sum_d Wk[h*64+d][c] * qh[h*64+d];  t[h] = qh_h . bk_h
__global__ __launch_bounds__(256) void k_m(
    const float* __restrict__ Win1, const float* __restrict__ bin1,
    float* __restrict__ ws)
{
    int idx = blockIdx.x * 256 + threadIdx.x;  // 0..4095
    int h = idx >> 9;
    int c = idx & (D - 1);
    const float* Wk = Win1 + D * D;            // rows 512..1023
    const float* q  = ws + WS_QH + h * DH;
    float acc = 0.f;
#pragma unroll 8
    for (int d = 0; d < DH; ++d) acc += Wk[(h * DH + d) * D + c] * q[d];
    ws[WS_M + idx] = acc;
    if (c == 0) {
        const float* bk = bin1 + D + h * DH;
        float tt = 0.f;
        for (int d = 0; d < DH; ++d) tt += bk[d] * q[d];
        ws[WS_T + h] = tt;
    }
}

// Kernel C (1 block, 512 thr): scores -> softmax -> cbar_h = sum_j w[h][j] ctx_j
__global__ __launch_bounds__(512) void k_attn(float* __restrict__ ws)
{
    __shared__ float s_lds[NH][CCTX];
    __shared__ float w_lds[NH][CCTX];
    int tid = threadIdx.x;

    // phase 1: score[h][j] = ctx_j . m_h  (8 lanes/row share broadcast addr)
    {
        int j = tid >> 3, h = tid & 7;
        const float* cr = ws + WS_CTX + j * D;
        const float* mr = ws + WS_M + h * D;
        float s = 0.f;
#pragma unroll 4
        for (int c4 = 0; c4 < 128; ++c4) {
            float4 a = *(const float4*)(cr + c4 * 4);
            float4 b = *(const float4*)(mr + c4 * 4);
            s += a.x*b.x + a.y*b.y + a.z*b.z + a.w*b.w;
        }
        s_lds[h][j] = (s + ws[WS_T + h]) * 0.125f;   // * DH^-0.5
    }
    __syncthreads();

    // phase 2: softmax per head, wave h handles its 64 scores
    {
        int h = tid >> 6, j = tid & 63;
        float sc = s_lds[h][j];
        float mx = sc;
#pragma unroll
        for (int off = 32; off > 0; off >>= 1) mx = fmaxf(mx, __shfl_xor(mx, off));
        float e = __expf(sc - mx);
        float sum = waveReduceSum(e);
        w_lds[h][j] = e / sum;
    }
    __syncthreads();

    // phase 3: cbar[h][c] — thread per column, ctx read exactly once (coalesced)
    {
        int c = tid;
        float acc[NH];
#pragma unroll
        for (int h = 0; h < NH; ++h) acc[h] = 0.f;
        for (int j = 0; j < CCTX; ++j) {
            float x = ws[WS_CTX + j * D + c];
#pragma unroll
            for (int h = 0; h < NH; ++h) acc[h] += w_lds[h][j] * x;
        }
#pragma unroll
        for (int h = 0; h < NH; ++h) ws[WS_CBAR + h * D + c] = acc[h];
    }
}

// Generic wave-per-row matvec: y[r] = W[r,:] . x(+head offset) + b[r], M=512 rows
__global__ __launch_bounds__(256) void k_matvec(
    const float* __restrict__ W, const float* __restrict__ x,
    const float* __restrict__ b, float* __restrict__ y, int headStride)
{
    int wid  = blockIdx.x * 4 + (threadIdx.x >> 6);
    int lane = threadIdx.x & 63;
    const float* xr = x + (wid >> 6) * headStride;
    const float* Wr = W + (size_t)wid * D;
    float4 w0 = *(const float4*)(Wr + lane * 4);
    float4 w1 = *(const float4*)(Wr + 256 + lane * 4);
    float4 x0 = *(const float4*)(xr + lane * 4);
    float4 x1 = *(const float4*)(xr + 256 + lane * 4);
    float s = w0.x*x0.x + w0.y*x0.y + w0.z*x0.z + w0.w*x0.w
            + w1.x*x1.x + w1.y*x1.y + w1.z*x1.z + w1.w*x1.w;
    s = waveReduceSum(s);
    if (lane == 0) y[wid] = s + b[wid];
}

// Matvec with fused pre-LayerNorm of its input: y = W @ (LN(pre+addv)*g+bln) + b
__global__ __launch_bounds__(256) void k_matvec_ln(
    const float* __restrict__ W, const float* __restrict__ pre,
    const float* __restrict__ addv, const float* __restrict__ g,
    const float* __restrict__ bln, const float* __restrict__ b,
    float* __restrict__ y)
{
    __shared__ __align__(16) float xs[D];
    __shared__ float red[8];
    int tid = threadIdx.x;
    float a0 = pre[tid * 2]     + addv[tid * 2];
    float a1 = pre[tid * 2 + 1] + addv[tid * 2 + 1];
    float s  = a0 + a1;
    float s2 = a0 * a0 + a1 * a1;
    s  = waveReduceSum(s);
    s2 = waveReduceSum(s2);
    int wib = tid >> 6, lane = tid & 63;
    if (lane == 0) { red[wib] = s; red[4 + wib] = s2; }
    __syncthreads();
    float st  = red[0] + red[1] + red[2] + red[3];
    float s2t = red[4] + red[5] + red[6] + red[7];
    float mu   = st * (1.f / D);
    float var  = s2t * (1.f / D) - mu * mu;
    float rinv = rsqrtf(var + LN_EPS);
    xs[tid * 2]     = (a0 - mu) * rinv * g[tid * 2]     + bln[tid * 2];
    xs[tid * 2 + 1] = (a1 - mu) * rinv * g[tid * 2 + 1] + bln[tid * 2 + 1];
    __syncthreads();
    int wid = blockIdx.x * 4 + wib;
    const float* Wr = W + (size_t)wid * D;
    float4 w0 = *(const float4*)(Wr + lane * 4);
    float4 w1 = *(const float4*)(Wr + 256 + lane * 4);
    float4 x0 = *(const float4*)(xs + lane * 4);
    float4 x1 = *(const float4*)(xs + 256 + lane * 4);
    float sd = w0.x*x0.x + w0.y*x0.y + w0.z*x0.z + w0.w*x0.w
             + w1.x*x1.x + w1.y*x1.y + w1.z*x1.z + w1.w*x1.w;
    sd = waveReduceSum(sd);
    if (lane == 0) y[wid] = sd + b[wid];
}

// Kernel H: H_cond[i,:] = LN(attn2 + H[i,:]) * g + b  — wave per row, grid-stride
__global__ __launch_bounds__(256) void k_final(
    const float* __restrict__ Hm, const float* __restrict__ attn2,
    const float* __restrict__ g, const float* __restrict__ b,
    float* __restrict__ out, int N)
{
    int lane = threadIdx.x & 63;
    int wib  = threadIdx.x >> 6;
    int c0 = lane * 4, c1 = 256 + lane * 4;
    float4 a0 = *(const float4*)(attn2 + c0), a1 = *(const float4*)(attn2 + c1);
    float4 g0 = *(const float4*)(g + c0),     g1 = *(const float4*)(g + c1);
    float4 b0 = *(const float4*)(b + c0),     b1 = *(const float4*)(b + c1);
    int stride = gridDim.x * 4;
    for (int row = blockIdx.x * 4 + wib; row < N; row += stride) {
        const float* hr = Hm + (size_t)row * D;
        float4 x0 = *(const float4*)(hr + c0);
        float4 x1 = *(const float4*)(hr + c1);
        x0.x += a0.x; x0.y += a0.y; x0.z += a0.z; x0.w += a0.w;
        x1.x += a1.x; x1.y += a1.y; x1.z += a1.z; x1.w += a1.w;
        float s  = x0.x + x0.y + x0.z + x0.w + x1.x + x1.y + x1.z + x1.w;
        float s2 = x0.x*x0.x + x0.y*x0.y + x0.z*x0.z + x0.w*x0.w
                 + x1.x*x1.x + x1.y*x1.y + x1.z*x1.z + x1.w*x1.w;
#pragma unroll
        for (int off = 32; off > 0; off >>= 1) {
            s  += __shfl_xor(s, off);
            s2 += __shfl_xor(s2, off);
        }
        float mu   = s * (1.f / D);
        float var  = s2 * (1.f / D) - mu * mu;
        float rinv = rsqrtf(var + LN_EPS);
        float4 y0, y1;
        y0.x = (x0.x - mu) * rinv * g0.x + b0.x;
        y0.y = (x0.y - mu) * rinv * g0.y + b0.y;
        y0.z = (x0.z - mu) * rinv * g0.z + b0.z;
        y0.w = (x0.w - mu) * rinv * g0.w + b0.w;
        y1.x = (x1.x - mu) * rinv * g1.x + b1.x;
        y1.y = (x1.y - mu) * rinv * g1.y + b1.y;
        y1.z = (x1.z - mu) * rinv * g1.z + b1.z;
        y1.w = (x1.w - mu) * rinv * g1.w + b1.w;
        float* orow = out + (size_t)row * D;
        *(float4*)(orow + c0) = y0;
        *(float4*)(orow + c1) = y1;
    }
}

extern "C" void kernel_launch(void* const* d_in, const int* in_sizes, int n_in,
                              void* d_out, int out_size, void* d_ws, size_t ws_size,
                              hipStream_t stream)
{
    const float* Hm    = (const float*)d_in[0];
    const float* path  = (const float*)d_in[1];
    const float* Win1  = (const float*)d_in[2];
    const float* bin1  = (const float*)d_in[3];
    const float* Wout1 = (const float*)d_in[4];
    const float* bout1 = (const float*)d_in[5];
    const float* Win2  = (const float*)d_in[6];
    const float* bin2  = (const float*)d_in[7];
    const float* Wout2 = (const float*)d_in[8];
    const float* bout2 = (const float*)d_in[9];
    const float* ln1g  = (const float*)d_in[10];
    const float* ln1b  = (const float*)d_in[11];
    const float* ln2g  = (const float*)d_in[12];
    const float* ln2b  = (const float*)d_in[13];
    // d_in[14] = edge_index — unused by the reference
    const int*   ids   = (const int*)d_in[15];

    float* ws  = (float*)d_ws;
    float* out = (float*)d_out;
    const int N = in_sizes[0] / D;

    // A: qh = Wq@path + bq ; gather ctx
    k_qh_gather<<<192, 256, 0, stream>>>(Win1, bin1, path, Hm, ids, ws);
    // B: m_h = Wk_h^T qh_h ; t_h = qh_h . bk_h
    k_m<<<16, 256, 0, stream>>>(Win1, bin1, ws);
    // C: scores -> softmax -> cbar
    k_attn<<<1, 512, 0, stream>>>(ws);
    // D: o[h*64+d] = Wv[h*64+d,:] . cbar_h + bv  (per-head x)
    k_matvec<<<128, 256, 0, stream>>>(Win1 + 2 * D * D, ws + WS_CBAR,
                                      bin1 + 2 * D, ws + WS_O, D);
    // E: out1 = W_out1 @ o + b_out1
    k_matvec<<<128, 256, 0, stream>>>(Wout1, ws + WS_O, bout1, ws + WS_OUT1, 0);
    // F: v = Wv2 @ LN(out1 + path) + bv2   (fused pre-LN)
    k_matvec_ln<<<128, 256, 0, stream>>>(Win2 + 2 * D * D, ws + WS_OUT1, path,
                                         ln1g, ln1b, bin2 + 2 * D, ws + WS_V);
    // G: attn2 = W_out2 @ v + b_out2
    k_matvec<<<128, 256, 0, stream>>>(Wout2, ws + WS_V, bout2, ws + WS_ATTN2, 0);
    // H: H_cond = LN(attn2 + H) * g2 + b2
    k_final<<<2048, 256, 0, stream>>>(Hm, ws + WS_ATTN2, ln2g, ln2b, out, N);
}